// Round 1
// baseline (976.762 us; speedup 1.0000x reference)
//
#include <hip/hip_runtime.h>
#include <hip/hip_bf16.h>

#define BB 64
#define NN 2048
#define CC 64
#define EE 16
#define OO 64
#define JJ 4096  // BB*CC

// ---------------- Kernel 1: A = softmax(relu(E E^T), axis=1) ----------------
__global__ __launch_bounds__(256) void supports_kernel(
    const float* __restrict__ emb, float* __restrict__ A)
{
  int n = blockIdx.x;
  int tid = threadIdx.x;
  float en[EE];
#pragma unroll
  for (int d = 0; d < EE; ++d) en[d] = emb[n*EE + d];

  float logit[8];
  float lmax = 0.0f;  // relu >= 0 and zeros are present in every row
#pragma unroll
  for (int i = 0; i < 8; ++i) {
    int m = i*256 + tid;
    const float* em = emb + m*EE;
    float s = 0.f;
#pragma unroll
    for (int d = 0; d < EE; ++d) s = fmaf(en[d], em[d], s);
    s = fmaxf(s, 0.f);
    logit[i] = s;
    lmax = fmaxf(lmax, s);
  }
  __shared__ float red[256];
  red[tid] = lmax; __syncthreads();
  for (int s = 128; s > 0; s >>= 1) {
    if (tid < s) red[tid] = fmaxf(red[tid], red[tid+s]);
    __syncthreads();
  }
  lmax = red[0]; __syncthreads();
  float sum = 0.f;
#pragma unroll
  for (int i = 0; i < 8; ++i) {
    float e = __expf(logit[i]-lmax);
    logit[i] = e; sum += e;
  }
  red[tid] = sum; __syncthreads();
  for (int s = 128; s > 0; s >>= 1) {
    if (tid < s) red[tid] += red[tid+s];
    __syncthreads();
  }
  float inv = 1.f/red[0];
#pragma unroll
  for (int i = 0; i < 8; ++i) A[(size_t)n*NN + i*256 + tid] = logit[i]*inv;
}

// ---------------- Kernel 2: Y[m,j] = sum_k Am[m,k] * X[k,j] ----------------
// Logical X is [2048, 4096]; physical addr = (j>>6)*seg_stride + k*row_stride + (j&63).
//   pass 1 (X = x [B,N,C]):  seg_stride = NN*CC = 131072, row_stride = 64
//   pass 2 (X = Y1 [N,J]):   seg_stride = 64,             row_stride = 4096
__global__ __launch_bounds__(256) void gemm_fp32(
    const float* __restrict__ Am, const float* __restrict__ X,
    float* __restrict__ Y, int seg_stride, int row_stride)
{
  __shared__ float At[32][132];   // A tile transposed [k][m], pad 132 (16B-aligned rows)
  __shared__ float Xs[32][128];   // X tile [k][j]
  int tid = threadIdx.x;
  int tx = tid & 15, ty = tid >> 4;
  int m0 = blockIdx.y * 128;
  int j0 = blockIdx.x * 128;

  float acc[2][2][4][4];
#pragma unroll
  for (int a = 0; a < 2; ++a)
#pragma unroll
    for (int b = 0; b < 2; ++b)
#pragma unroll
      for (int i = 0; i < 4; ++i)
#pragma unroll
        for (int j = 0; j < 4; ++j) acc[a][b][i][j] = 0.f;

  for (int k0 = 0; k0 < 2048; k0 += 32) {
    // stage A tile (128 rows x 32 k), transposed into LDS
#pragma unroll
    for (int p = 0; p < 4; ++p) {
      int idx = tid + p*256;
      int r = idx >> 3, c4 = (idx & 7)*4;
      float4 v = *(const float4*)(Am + (size_t)(m0 + r)*2048 + k0 + c4);
      At[c4+0][r] = v.x; At[c4+1][r] = v.y; At[c4+2][r] = v.z; At[c4+3][r] = v.w;
    }
    // stage X tile (32 k x 128 j)
#pragma unroll
    for (int p = 0; p < 4; ++p) {
      int idx = tid + p*256;
      int r = idx >> 5, q = idx & 31;
      int j = j0 + q*4;
      float4 v = *(const float4*)(X + (size_t)(j>>6)*seg_stride + (size_t)(k0 + r)*row_stride + (j&63));
      *(float4*)&Xs[r][q*4] = v;
    }
    __syncthreads();
#pragma unroll
    for (int kk = 0; kk < 32; ++kk) {
      float4 a0 = *(const float4*)&At[kk][ty*4];
      float4 a1 = *(const float4*)&At[kk][64 + ty*4];
      float4 x0 = *(const float4*)&Xs[kk][tx*4];
      float4 x1 = *(const float4*)&Xs[kk][64 + tx*4];
      float ar[2][4] = {{a0.x,a0.y,a0.z,a0.w},{a1.x,a1.y,a1.z,a1.w}};
      float xr[2][4] = {{x0.x,x0.y,x0.z,x0.w},{x1.x,x1.y,x1.z,x1.w}};
#pragma unroll
      for (int rc = 0; rc < 2; ++rc)
#pragma unroll
        for (int cc = 0; cc < 2; ++cc)
#pragma unroll
          for (int i = 0; i < 4; ++i)
#pragma unroll
            for (int j = 0; j < 4; ++j)
              acc[rc][cc][i][j] = fmaf(ar[rc][i], xr[cc][j], acc[rc][cc][i][j]);
    }
    __syncthreads();
  }
  // epilogue: Y stored [N, 4096] row-major
#pragma unroll
  for (int rc = 0; rc < 2; ++rc)
#pragma unroll
    for (int i = 0; i < 4; ++i) {
      int m = m0 + rc*64 + ty*4 + i;
#pragma unroll
      for (int cc = 0; cc < 2; ++cc) {
        float4 v = make_float4(acc[rc][cc][i][0], acc[rc][cc][i][1],
                               acc[rc][cc][i][2], acc[rc][cc][i][3]);
        *(float4*)(Y + (size_t)m*4096 + j0 + cc*64 + tx*4) = v;
      }
    }
}

// ---------------- Kernel 3: per-node dynamic-weight grouped GEMM ----------------
// out[b,n,o] = sum_{kc} XgT[kc][b] * W_n[kc][o] + bias_n[o]
__global__ __launch_bounds__(256) void final_kernel(
    const float* __restrict__ x, const float* __restrict__ emb,
    const float* __restrict__ wp, const float* __restrict__ bp,
    const float* __restrict__ y1, const float* __restrict__ y2,
    float* __restrict__ out)
{
  int n = blockIdx.x;
  int tid = threadIdx.x;
  __shared__ float W[192][64];     // 48 KB: per-node weights [kc][o]
  __shared__ float XgT[192][68];   // ~51 KB: gathered features [kc][b], pad 68 (16B-aligned)
  __shared__ float bias_s[64];
  __shared__ float e_s[16];
  if (tid < 16) e_s[tid] = emb[n*16 + tid];
  __syncthreads();

  // W_n[kc][o] = sum_d e[d] * wp[d][kc][o]   (wp flat: d*12288 + kc*64 + o)
  for (int p = 0; p < 48; ++p) {
    int idx = tid + p*256;          // 0..12287
    float s = 0.f;
#pragma unroll
    for (int d = 0; d < 16; ++d) s = fmaf(e_s[d], wp[d*12288 + idx], s);
    W[idx >> 6][idx & 63] = s;
  }
  if (tid < 64) {
    float s = 0.f;
#pragma unroll
    for (int d = 0; d < 16; ++d) s = fmaf(e_s[d], bp[d*64 + tid], s);
    bias_s[tid] = s;
  }
  // gather Xg: kc = k*64 + c;  k=0 -> x, k=1 -> y1, k=2 -> 2*y2 - x
#pragma unroll
  for (int p = 0; p < 4; ++p) {
    int t = tid + p*256;            // 0..1023
    int b = t >> 4, c4 = (t & 15)*4;
    float4 xv = *(const float4*)(x  + ((size_t)b*2048 + n)*64 + c4);
    float4 v1 = *(const float4*)(y1 + (size_t)n*4096 + b*64 + c4);
    float4 v2 = *(const float4*)(y2 + (size_t)n*4096 + b*64 + c4);
    XgT[c4+0][b] = xv.x; XgT[c4+1][b] = xv.y; XgT[c4+2][b] = xv.z; XgT[c4+3][b] = xv.w;
    XgT[64+c4+0][b] = v1.x; XgT[64+c4+1][b] = v1.y; XgT[64+c4+2][b] = v1.z; XgT[64+c4+3][b] = v1.w;
    XgT[128+c4+0][b] = 2.f*v2.x - xv.x; XgT[128+c4+1][b] = 2.f*v2.y - xv.y;
    XgT[128+c4+2][b] = 2.f*v2.z - xv.z; XgT[128+c4+3][b] = 2.f*v2.w - xv.w;
  }
  __syncthreads();

  int tx = tid & 15, ty = tid >> 4;   // output tile: b = ty*4+i, o = tx*4+j
  float acc[4][4];
#pragma unroll
  for (int i = 0; i < 4; ++i)
#pragma unroll
    for (int j = 0; j < 4; ++j) acc[i][j] = bias_s[tx*4+j];

  for (int kc = 0; kc < 192; ++kc) {
    float4 a = *(const float4*)&XgT[kc][ty*4];
    float4 w = *(const float4*)&W[kc][tx*4];
    float ar[4] = {a.x, a.y, a.z, a.w};
    float wr[4] = {w.x, w.y, w.z, w.w};
#pragma unroll
    for (int i = 0; i < 4; ++i)
#pragma unroll
      for (int j = 0; j < 4; ++j)
        acc[i][j] = fmaf(ar[i], wr[j], acc[i][j]);
  }
#pragma unroll
  for (int i = 0; i < 4; ++i) {
    float4 v = make_float4(acc[i][0], acc[i][1], acc[i][2], acc[i][3]);
    *(float4*)(out + ((size_t)(ty*4+i)*2048 + n)*64 + tx*4) = v;
  }
}

extern "C" void kernel_launch(void* const* d_in, const int* in_sizes, int n_in,
                              void* d_out, int out_size, void* d_ws, size_t ws_size,
                              hipStream_t stream) {
  const float* x   = (const float*)d_in[0];   // [64, 2048, 64]
  const float* emb = (const float*)d_in[1];   // [2048, 16]
  const float* wp  = (const float*)d_in[2];   // [16, 3, 64, 64]
  const float* bp  = (const float*)d_in[3];   // [16, 64]
  float* out = (float*)d_out;                 // [64, 2048, 64]

  float* A  = (float*)d_ws;                   // [2048, 2048]   16.8 MB
  float* Y1 = A  + (size_t)NN*NN;             // [2048, 4096]   33.5 MB
  float* Y2 = Y1 + (size_t)NN*JJ;             // [2048, 4096]   33.5 MB

  supports_kernel<<<NN, 256, 0, stream>>>(emb, A);
  dim3 g(JJ/128, NN/128);  // (32, 16)
  gemm_fp32<<<g, 256, 0, stream>>>(A, x,  Y1, NN*CC, 64);   // Y1 = A @ X
  gemm_fp32<<<g, 256, 0, stream>>>(A, Y1, Y2, 64,  4096);   // Y2 = A @ Y1
  final_kernel<<<NN, 256, 0, stream>>>(x, emb, wp, bp, Y1, Y2, out);
}

// Round 2
// 275.595 us; speedup vs baseline: 3.5442x; 3.5442x over previous
//
#include <hip/hip_runtime.h>
#include <hip/hip_bf16.h>

#define BB 64
#define NN 2048
#define CC 64
#define EE 16
#define OO 64
#define JJ 4096  // BB*CC

typedef __attribute__((ext_vector_type(8))) short short8;
typedef __attribute__((ext_vector_type(4))) float f32x4;
typedef __attribute__((ext_vector_type(4))) unsigned short u16x4;
typedef __attribute__((ext_vector_type(8))) unsigned short u16x8;

__device__ __forceinline__ unsigned short f2bf(float f) {
  __hip_bfloat16 h = __float2bfloat16(f);
  return *reinterpret_cast<unsigned short*>(&h);
}
__device__ __forceinline__ float bf2f(unsigned short u) {
  unsigned int v = ((unsigned int)u) << 16;
  return *reinterpret_cast<float*>(&v);
}
__device__ __forceinline__ void gload16(const void* g, void* l) {
  __builtin_amdgcn_global_load_lds(
      (const __attribute__((address_space(1))) unsigned int*)g,
      (__attribute__((address_space(3))) unsigned int*)l, 16, 0, 0);
}

// ---------------- Kernel 1: Ab = bf16(softmax(relu(E E^T), axis=1)) ----------------
__global__ __launch_bounds__(256) void supports_kernel(
    const float* __restrict__ emb, unsigned short* __restrict__ A)
{
  int n = blockIdx.x;
  int tid = threadIdx.x;
  float en[EE];
#pragma unroll
  for (int d = 0; d < EE; ++d) en[d] = emb[n*EE + d];

  float logit[8];
  float lmax = 0.0f;  // relu >= 0
#pragma unroll
  for (int i = 0; i < 8; ++i) {
    int m = i*256 + tid;
    const float* em = emb + m*EE;
    float s = 0.f;
#pragma unroll
    for (int d = 0; d < EE; ++d) s = fmaf(en[d], em[d], s);
    s = fmaxf(s, 0.f);
    logit[i] = s;
    lmax = fmaxf(lmax, s);
  }
  __shared__ float red[256];
  red[tid] = lmax; __syncthreads();
  for (int s = 128; s > 0; s >>= 1) {
    if (tid < s) red[tid] = fmaxf(red[tid], red[tid+s]);
    __syncthreads();
  }
  lmax = red[0]; __syncthreads();
  float sum = 0.f;
#pragma unroll
  for (int i = 0; i < 8; ++i) {
    float e = __expf(logit[i]-lmax);
    logit[i] = e; sum += e;
  }
  red[tid] = sum; __syncthreads();
  for (int s = 128; s > 0; s >>= 1) {
    if (tid < s) red[tid] += red[tid+s];
    __syncthreads();
  }
  float inv = 1.f/red[0];
#pragma unroll
  for (int i = 0; i < 8; ++i) A[(size_t)n*NN + i*256 + tid] = f2bf(logit[i]*inv);
}

// ---------------- Kernel 1b: Xt[b*64+c][n] = bf16(x[b][n][c]) ----------------
__global__ __launch_bounds__(256) void xpose_kernel(
    const float* __restrict__ x, unsigned short* __restrict__ Xt)
{
  int b = blockIdx.y;        // 64
  int n0 = blockIdx.x * 64;  // 32
  __shared__ float T[64][65];
  int tid = threadIdx.x;
  int r = tid >> 4, c4 = (tid & 15) * 4;
  const float* src = x + ((size_t)b*NN + n0)*64;
#pragma unroll
  for (int rr = r; rr < 64; rr += 16) {
    float4 v = *(const float4*)(src + rr*64 + c4);
    T[rr][c4] = v.x; T[rr][c4+1] = v.y; T[rr][c4+2] = v.z; T[rr][c4+3] = v.w;
  }
  __syncthreads();
  int c = tid >> 2, q0 = (tid & 3) * 16;   // 16 bf16 per thread along n
  unsigned short* dst = Xt + ((size_t)b*64 + c)*NN + n0 + q0;
  u16x8 o0, o1;
#pragma unroll
  for (int q = 0; q < 8; ++q) o0[q] = f2bf(T[q0+q][c]);
#pragma unroll
  for (int q = 0; q < 8; ++q) o1[q] = f2bf(T[q0+8+q][c]);
  *(u16x8*)(dst) = o0;
  *(u16x8*)(dst + 8) = o1;
}

// ---------------- Kernel 2: bf16 MFMA GEMM, C[m][j] = sum_k A[m][k]*Bt[j][k] ----------------
// A  : bf16 [2048][2048] row-major (k contiguous)
// Bt : bf16 [4096][2048] row-major (k contiguous)  == B^T
// Crow: bf16 [2048][4096]  (always written)
// Ct  : bf16 [4096][2048]  (written iff writeT) — transposed output for next pass
__global__ __launch_bounds__(256) void gemm_bt_bf16(
    const unsigned short* __restrict__ A, const unsigned short* __restrict__ Bt,
    unsigned short* __restrict__ Crow, unsigned short* __restrict__ Ct, int writeT)
{
  __shared__ unsigned short As[128*64];  // [row][k] with 16B-unit XOR swizzle
  __shared__ unsigned short Bs[128*64];
  int tid = threadIdx.x;
  int bid = blockIdx.x;
  int swz = (bid & 7) * 64 + (bid >> 3);    // 512 blocks -> XCD-contiguous chunks
  int m0 = (swz >> 5) * 128, j0 = (swz & 31) * 128;
  int wid = tid >> 6, lane = tid & 63;
  int wm = wid >> 1, wn = wid & 1;          // 2x2 wave grid, 64x64 per wave
  int fr = lane & 15, kg = lane >> 4;
  int lrow = lane >> 3, lu = lane & 7;      // staging: 8 rows x 8 units per wave-load

  f32x4 acc[4][4];
#pragma unroll
  for (int i = 0; i < 4; ++i)
#pragma unroll
    for (int j = 0; j < 4; ++j) acc[i][j] = (f32x4){0.f,0.f,0.f,0.f};

  for (int k0 = 0; k0 < 2048; k0 += 64) {
    // stage A,B tiles: LDS[row][u] = global[row][u ^ (row&7)] (pre-swizzled source)
#pragma unroll
    for (int li = 0; li < 4; ++li) {
      int rb = wid*32 + li*8;
      int r = rb + lrow;
      int su = lu ^ (r & 7);
      gload16(A  + (size_t)(m0 + r)*2048 + k0 + su*8, &As[rb*64]);
      gload16(Bt + (size_t)(j0 + r)*2048 + k0 + su*8, &Bs[rb*64]);
    }
    asm volatile("s_waitcnt vmcnt(0)" ::: "memory");
    __syncthreads();
#pragma unroll
    for (int ks = 0; ks < 2; ++ks) {
      short8 af[4], bv[4];
#pragma unroll
      for (int i = 0; i < 4; ++i) {
        int r = wm*64 + i*16 + fr;
        int u = ((ks << 2) | kg) ^ (r & 7);
        af[i] = *(const short8*)((const char*)As + r*128 + u*16);
      }
#pragma unroll
      for (int j = 0; j < 4; ++j) {
        int r = wn*64 + j*16 + fr;
        int u = ((ks << 2) | kg) ^ (r & 7);
        bv[j] = *(const short8*)((const char*)Bs + r*128 + u*16);
      }
#pragma unroll
      for (int i = 0; i < 4; ++i)
#pragma unroll
        for (int j = 0; j < 4; ++j)
          acc[i][j] = __builtin_amdgcn_mfma_f32_16x16x32_bf16(af[i], bv[j], acc[i][j], 0, 0, 0);
    }
    __syncthreads();
  }
  // epilogue: C/D frag -> col = lane&15 (j), row = (lane>>4)*4 + reg (m)
  int mrow4 = (lane >> 4) * 4;
#pragma unroll
  for (int i = 0; i < 4; ++i) {
    int mbase = m0 + wm*64 + i*16 + mrow4;
#pragma unroll
    for (int j = 0; j < 4; ++j) {
      int jcol = j0 + wn*64 + j*16 + fr;
      f32x4 v = acc[i][j];
      if (writeT) {
        u16x4 pk = { f2bf(v[0]), f2bf(v[1]), f2bf(v[2]), f2bf(v[3]) };
        *(u16x4*)(Ct + (size_t)jcol*2048 + mbase) = pk;
      }
      Crow[(size_t)(mbase+0)*4096 + jcol] = f2bf(v[0]);
      Crow[(size_t)(mbase+1)*4096 + jcol] = f2bf(v[1]);
      Crow[(size_t)(mbase+2)*4096 + jcol] = f2bf(v[2]);
      Crow[(size_t)(mbase+3)*4096 + jcol] = f2bf(v[3]);
    }
  }
}

// ---------------- Kernel 3: per-node dynamic-weight grouped GEMM ----------------
__global__ __launch_bounds__(256) void final_kernel(
    const float* __restrict__ x, const float* __restrict__ emb,
    const float* __restrict__ wp, const float* __restrict__ bp,
    const unsigned short* __restrict__ y1, const unsigned short* __restrict__ y2,
    float* __restrict__ out)
{
  int n = blockIdx.x;
  int tid = threadIdx.x;
  __shared__ float W[192][64];     // 48 KB
  __shared__ float XgT[192][68];   // ~51 KB, pad 68
  __shared__ float bias_s[64];
  __shared__ float e_s[16];
  if (tid < 16) e_s[tid] = emb[n*16 + tid];
  __syncthreads();

  for (int p = 0; p < 48; ++p) {
    int idx = tid + p*256;          // 0..12287
    float s = 0.f;
#pragma unroll
    for (int d = 0; d < 16; ++d) s = fmaf(e_s[d], wp[d*12288 + idx], s);
    W[idx >> 6][idx & 63] = s;
  }
  if (tid < 64) {
    float s = 0.f;
#pragma unroll
    for (int d = 0; d < 16; ++d) s = fmaf(e_s[d], bp[d*64 + tid], s);
    bias_s[tid] = s;
  }
#pragma unroll
  for (int p = 0; p < 4; ++p) {
    int t = tid + p*256;            // 0..1023
    int b = t >> 4, c4 = (t & 15)*4;
    float4 xv = *(const float4*)(x + ((size_t)b*NN + n)*64 + c4);
    u16x4 v1 = *(const u16x4*)(y1 + (size_t)n*4096 + b*64 + c4);
    u16x4 v2 = *(const u16x4*)(y2 + (size_t)n*4096 + b*64 + c4);
    float f1[4] = {bf2f(v1[0]), bf2f(v1[1]), bf2f(v1[2]), bf2f(v1[3])};
    float f2[4] = {bf2f(v2[0]), bf2f(v2[1]), bf2f(v2[2]), bf2f(v2[3])};
    float xr[4] = {xv.x, xv.y, xv.z, xv.w};
#pragma unroll
    for (int q = 0; q < 4; ++q) {
      XgT[c4+q][b]     = xr[q];
      XgT[64+c4+q][b]  = f1[q];
      XgT[128+c4+q][b] = 2.f*f2[q] - xr[q];
    }
  }
  __syncthreads();

  int tx = tid & 15, ty = tid >> 4;   // b = ty*4+i, o = tx*4+j
  float acc[4][4];
#pragma unroll
  for (int i = 0; i < 4; ++i)
#pragma unroll
    for (int j = 0; j < 4; ++j) acc[i][j] = bias_s[tx*4+j];

  for (int kc = 0; kc < 192; ++kc) {
    float4 a = *(const float4*)&XgT[kc][ty*4];
    float4 w = *(const float4*)&W[kc][tx*4];
    float ar[4] = {a.x, a.y, a.z, a.w};
    float wr[4] = {w.x, w.y, w.z, w.w};
#pragma unroll
    for (int i = 0; i < 4; ++i)
#pragma unroll
      for (int j = 0; j < 4; ++j)
        acc[i][j] = fmaf(ar[i], wr[j], acc[i][j]);
  }
#pragma unroll
  for (int i = 0; i < 4; ++i) {
    float4 v = make_float4(acc[i][0], acc[i][1], acc[i][2], acc[i][3]);
    *(float4*)(out + ((size_t)(ty*4+i)*NN + n)*64 + tx*4) = v;
  }
}

extern "C" void kernel_launch(void* const* d_in, const int* in_sizes, int n_in,
                              void* d_out, int out_size, void* d_ws, size_t ws_size,
                              hipStream_t stream) {
  const float* x   = (const float*)d_in[0];   // [64, 2048, 64]
  const float* emb = (const float*)d_in[1];   // [2048, 16]
  const float* wp  = (const float*)d_in[2];   // [16, 3, 64, 64]
  const float* bp  = (const float*)d_in[3];   // [16, 64]
  float* out = (float*)d_out;                 // [64, 2048, 64]

  unsigned short* Ab  = (unsigned short*)d_ws;        // [2048][2048] bf16  8.4 MB
  unsigned short* Xt  = Ab  + (size_t)NN*NN;          // [4096][2048] bf16 16.8 MB
  unsigned short* Y1T = Xt  + (size_t)JJ*NN;          // [4096][2048] bf16 16.8 MB
  unsigned short* Y1b = Y1T + (size_t)JJ*NN;          // [2048][4096] bf16 16.8 MB
  unsigned short* Y2b = Y1b + (size_t)NN*JJ;          // [2048][4096] bf16 16.8 MB

  supports_kernel<<<NN, 256, 0, stream>>>(emb, Ab);
  xpose_kernel<<<dim3(32, 64), 256, 0, stream>>>(x, Xt);
  gemm_bt_bf16<<<512, 256, 0, stream>>>(Ab, Xt,  Y1b, Y1T, 1);      // Y1 = A @ X
  gemm_bt_bf16<<<512, 256, 0, stream>>>(Ab, Y1T, Y2b, nullptr, 0);  // Y2 = A @ Y1
  final_kernel<<<NN, 256, 0, stream>>>(x, emb, wp, bp, Y1b, Y2b, out);
}